// Round 14
// baseline (145.955 us; speedup 1.0000x reference)
//
#include <hip/hip_runtime.h>
#include <math.h>

#define BS   8192
#define DIM  256
#define KNEG 16
#define GAMMA (1.0f / 0.07f)
#define EXP_CLAMP 60.0f   // e^60*8192*16 ~ 1.5e31 < FLT_MAX: sums stay finite
#define NSTRIPS 8

typedef float v4f  __attribute__((ext_vector_type(4)));
typedef short s8b  __attribute__((ext_vector_type(8)));   // 8 bf16 as shorts

__device__ __forceinline__ float sat_exp(float dot) {
    float a = 2.0f * GAMMA * dot - 2.0f * GAMMA;
    return expf(fminf(a, EXP_CLAMP));
}

// compare-exchange: x=min, y=max (2 VALU, no selects)
__device__ __forceinline__ void ce(float& x, float& y) {
    float lo = fminf(x, y), hi = fmaxf(x, y);
    x = lo; y = hi;
}

// Batcher odd-even merge sort, 16 inputs, ascending. 63 CE.
__device__ __forceinline__ void sort16(float (&a)[16]) {
    ce(a[0],a[1]); ce(a[2],a[3]); ce(a[4],a[5]); ce(a[6],a[7]);
    ce(a[8],a[9]); ce(a[10],a[11]); ce(a[12],a[13]); ce(a[14],a[15]);
    ce(a[0],a[2]); ce(a[1],a[3]); ce(a[4],a[6]); ce(a[5],a[7]);
    ce(a[8],a[10]); ce(a[9],a[11]); ce(a[12],a[14]); ce(a[13],a[15]);
    ce(a[1],a[2]); ce(a[5],a[6]); ce(a[9],a[10]); ce(a[13],a[14]);
    ce(a[0],a[4]); ce(a[1],a[5]); ce(a[2],a[6]); ce(a[3],a[7]);
    ce(a[8],a[12]); ce(a[9],a[13]); ce(a[10],a[14]); ce(a[11],a[15]);
    ce(a[2],a[4]); ce(a[3],a[5]); ce(a[10],a[12]); ce(a[11],a[13]);
    ce(a[1],a[2]); ce(a[3],a[4]); ce(a[5],a[6]);
    ce(a[9],a[10]); ce(a[11],a[12]); ce(a[13],a[14]);
    ce(a[0],a[8]); ce(a[1],a[9]); ce(a[2],a[10]); ce(a[3],a[11]);
    ce(a[4],a[12]); ce(a[5],a[13]); ce(a[6],a[14]); ce(a[7],a[15]);
    ce(a[4],a[8]); ce(a[5],a[9]); ce(a[6],a[10]); ce(a[7],a[11]);
    ce(a[2],a[4]); ce(a[3],a[5]); ce(a[6],a[8]); ce(a[7],a[9]);
    ce(a[10],a[12]); ce(a[11],a[13]);
    ce(a[1],a[2]); ce(a[3],a[4]); ce(a[5],a[6]); ce(a[7],a[8]);
    ce(a[9],a[10]); ce(a[11],a[12]); ce(a[13],a[14]);
}

// merge two ascending sorted-16, keep top-16 ascending (16 max + 32 CE)
__device__ __forceinline__ void merge_top16(float (&lst)[16], const float (&nw)[16]) {
#pragma unroll
    for (int i = 0; i < 16; ++i) lst[i] = fmaxf(lst[i], nw[15 - i]);
#pragma unroll
    for (int j = 8; j > 0; j >>= 1)
#pragma unroll
        for (int i = 0; i < 16; ++i) {
            int ixj = i ^ j;
            if (ixj > i) ce(lst[i], lst[ixj]);
        }
}

// legacy insertion helper (fallback path only)
__device__ __forceinline__ void topk_insert(float (&lst)[16], float v) {
    float nl[16];
#pragma unroll
    for (int u = 0; u < 15; ++u)
        nl[u] = (v > lst[u + 1]) ? lst[u + 1] : ((v > lst[u]) ? v : lst[u]);
    nl[15] = (v > lst[15]) ? v : lst[15];
#pragma unroll
    for (int u = 0; u < 16; ++u) lst[u] = nl[u];
}

__device__ __forceinline__ unsigned short f2bf_rne(float f) {
    unsigned int u = __float_as_uint(f);
    u += 0x7FFFu + ((u >> 16) & 1u);
    return (unsigned short)(u >> 16);
}

__device__ __forceinline__ void gld_lds16(const void* g, void* l) {
    __builtin_amdgcn_global_load_lds(
        (const __attribute__((address_space(1))) void*)g,
        (__attribute__((address_space(3))) void*)l, 16, 0, 0);
}

__device__ __forceinline__ float finite_or(float x, float repl) {
    if (isnan(x)) return repl;
    if (isinf(x)) return x > 0.0f ? 3.0e38f : -3.0e38f;
    return x;
}

// ------- conv_pos: fp32 -> bf16 pre-convert + per-block diagonal partials -----
// Also zeroes the stage2 ticket (runs strictly before stage2 on the stream).
__global__ void conv_pos(const float* __restrict__ feat,
                         unsigned short* __restrict__ featbf,
                         float* __restrict__ partialPos,
                         unsigned int* __restrict__ ticket) {
    __shared__ float red[8];
    if (blockIdx.x == 0 && threadIdx.x == 0) *ticket = 0u;
    int t = blockIdx.x * 256 + threadIdx.x;   // 0..262143
    int row = t >> 5;
    int c = t & 31;                           // 8-float chunk within the 256-dim
    const float* f1 = feat + (size_t)row * 512 + c * 8;
    const float* f2 = f1 + 256;
    float4 a0 = *(const float4*)(f1);
    float4 a1 = *(const float4*)(f1 + 4);
    float4 b0 = *(const float4*)(f2);
    float4 b1 = *(const float4*)(f2 + 4);
    uint4 pa, pb;
    pa.x = (unsigned)f2bf_rne(a0.x) | ((unsigned)f2bf_rne(a0.y) << 16);
    pa.y = (unsigned)f2bf_rne(a0.z) | ((unsigned)f2bf_rne(a0.w) << 16);
    pa.z = (unsigned)f2bf_rne(a1.x) | ((unsigned)f2bf_rne(a1.y) << 16);
    pa.w = (unsigned)f2bf_rne(a1.z) | ((unsigned)f2bf_rne(a1.w) << 16);
    pb.x = (unsigned)f2bf_rne(b0.x) | ((unsigned)f2bf_rne(b0.y) << 16);
    pb.y = (unsigned)f2bf_rne(b0.z) | ((unsigned)f2bf_rne(b0.w) << 16);
    pb.z = (unsigned)f2bf_rne(b1.x) | ((unsigned)f2bf_rne(b1.y) << 16);
    pb.w = (unsigned)f2bf_rne(b1.z) | ((unsigned)f2bf_rne(b1.w) << 16);
    *(uint4*)(featbf + (size_t)row * 512 + c * 8) = pa;
    *(uint4*)(featbf + (size_t)row * 512 + 256 + c * 8) = pb;
    float p = a0.x * b0.x + a0.y * b0.y + a0.z * b0.z + a0.w * b0.w
            + a1.x * b1.x + a1.y * b1.y + a1.z * b1.z + a1.w * b1.w;
#pragma unroll
    for (int o = 16; o; o >>= 1) p += __shfl_xor(p, o, 32);
    if (c == 0) red[threadIdx.x >> 5] = sat_exp(p);
    __syncthreads();
    if (threadIdx.x == 0) {
        float s = 0.0f;
#pragma unroll
        for (int i = 0; i < 8; ++i) s += red[i];
        partialPos[blockIdx.x] = s;
    }
}

// ------- stage1: 24 KB LDS, 4 blk/CU, zero tail; B chunk-major (bank-clean) ---
// Block 256 thr = 4 waves (wy=row-half, wx=col-half). 16x16x32 MFMA.
// Per k-step buffer (12 KB): A [128 F2 rows][64 B] @0, B chunk-major @8192.
// B mapping: inst w covers rows 16w..16w+15; lane l -> row 16w+(l&15),
//   k-chunk (l>>4)^(l&3). Frag (rl,quad) at slot ((quad^(rl&3))<<4)|(rl&15)
//   -> bank start (rl&7)*4 -> 2-way aliasing (free).
// Double-buffered, one barrier per k-step, prefetch issued post-barrier.
#define BUFSZ  12288
#define S1_LDS 24576

__global__ __launch_bounds__(256, 4) void stage1(const unsigned short* __restrict__ featbf,
                                                 float* __restrict__ wsTop) {
    __shared__ __align__(16) char smem[S1_LDS];
    const int t = threadIdx.x;
    const int l = t & 63;
    const int w = t >> 6;
    const int wy = w >> 1, wx = w & 1;
    const int quad = l >> 4, lane16 = l & 15;
    const int nbase = blockIdx.x * 64;
    const int strip = blockIdx.y;

    float lst[2][16];
#pragma unroll
    for (int ni = 0; ni < 2; ++ni)
#pragma unroll
        for (int i = 0; i < 16; ++i) lst[ni][i] = -INFINITY;

    const int akey = (quad ^ ((lane16 >> 1) & 3)) * 16;       // A frag slot offset
    const int bkey = (quad ^ (lane16 & 3)) * 256 + lane16 * 16; // B frag slot offset
    // A staging per-lane offsets: inst jj (j=w*2+jj) covers rows 16j..16j+15;
    // lane l -> row ra = 16j+(l>>2), slot l&3, chunk ca=(l&3)^((ra>>1)&3)
    int ab[2];
#pragma unroll
    for (int jj = 0; jj < 2; ++jj) {
        int ra = 16 * (w * 2 + jj) + (l >> 2);
        int ca = (l & 3) ^ ((ra >> 1) & 3);
        ab[jj] = (ra << 9) + ca * 8;
    }
    // B staging per-lane offset (chunk-major): row rb = 16w+(l&15),
    // content chunk cb = (l>>4)^(l&3)
    int bb;
    {
        int rb = 16 * w + (l & 15);
        int cb = (l >> 4) ^ (l & 3);
        bb = (rb << 9) + cb * 8;
    }
    const int ubase = nbase << 9;   // B uniform base (F1 at +0)

    // initial prefetch g=0 -> buf0
    {
        const int uA = (strip * 1024 << 9) + 256;
#pragma unroll
        for (int jj = 0; jj < 2; ++jj)
            gld_lds16(featbf + (size_t)(uA + ab[jj]), smem + (w * 2 + jj) * 1024);
        gld_lds16(featbf + (size_t)(ubase + bb), smem + 8192 + w * 1024);
    }

#pragma unroll 1
    for (int ct = 0; ct < 8; ++ct) {
        const int ctbase = strip * 1024 + ct * 128;
        v4f acc[4][2];
#pragma unroll
        for (int mi = 0; mi < 4; ++mi)
#pragma unroll
            for (int ni = 0; ni < 2; ++ni) acc[mi][ni] = (v4f)0.0f;

#pragma unroll
        for (int s = 0; s < 8; ++s) {
            __syncthreads();   // drains prefetch for THIS step (issued a phase ago)
            // prefetch next k-step into the other buffer
            if (ct < 7 || s < 7) {
                const int nct = (s == 7) ? ctbase + 128 : ctbase;
                const int ns = (s == 7) ? 0 : s + 1;
                const int uA = (nct << 9) + 256 + ns * 32;   // wave-uniform
                const int uB = ubase + ns * 32;
                char* dst = smem + ((s + 1) & 1) * BUFSZ;
#pragma unroll
                for (int jj = 0; jj < 2; ++jj)
                    gld_lds16(featbf + (size_t)(uA + ab[jj]),
                              dst + (w * 2 + jj) * 1024);
                gld_lds16(featbf + (size_t)(uB + bb), dst + 8192 + w * 1024);
            }
            // compute current k-step
            const char* Ab = smem + (s & 1) * BUFSZ;
            s8b a[4];
#pragma unroll
            for (int mi = 0; mi < 4; ++mi)
                a[mi] = *(const s8b*)(Ab + (wx * 64 + mi * 16 + lane16) * 64 + akey);
#pragma unroll
            for (int ni = 0; ni < 2; ++ni) {
                s8b b = *(const s8b*)(Ab + 8192 + (wy * 2 + ni) * 1024 + bkey);
#pragma unroll
                for (int mi = 0; mi < 4; ++mi)
                    acc[mi][ni] = __builtin_amdgcn_mfma_f32_16x16x32_bf16(
                        a[mi], b, acc[mi][ni], 0, 0, 0);
            }
        }
        // ---- batch scan: 16 fresh values per ni -> Batcher sort + merge ----
#pragma unroll
        for (int ni = 0; ni < 2; ++ni) {
            const int row = nbase + wy * 32 + ni * 16 + lane16;
            float nw[16];
#pragma unroll
            for (int mi = 0; mi < 4; ++mi) {
                const int c0 = ctbase + wx * 64 + mi * 16 + quad * 4;
#pragma unroll
                for (int r4 = 0; r4 < 4; ++r4) {
                    float v = acc[mi][ni][r4];
                    nw[mi * 4 + r4] = (c0 + r4 == row) ? -INFINITY : v;
                }
            }
            sort16(nw);
            merge_top16(lst[ni], nw);
        }
    }
    // ---- quad merge via xor-shfl (lists sorted ascending) ----
#pragma unroll
    for (int ni = 0; ni < 2; ++ni) {
#pragma unroll
        for (int r = 16; r <= 32; r <<= 1) {
            float nw[16];
#pragma unroll
            for (int i = 0; i < 16; ++i) nw[i] = __shfl(lst[ni][i], l ^ r, 64);
            merge_top16(lst[ni], nw);
        }
    }
    // ---- wx merge via LDS (buf0 idle after final compute) ----
    __syncthreads();
    float* mrg = (float*)smem;   // 64 rows x 16 f32 = 4 KB
    if (wx == 1 && quad == 0) {
#pragma unroll
        for (int ni = 0; ni < 2; ++ni) {
            int rl = wy * 32 + ni * 16 + lane16;
#pragma unroll
            for (int i = 0; i < 16; i += 4)
                *(v4f*)(mrg + rl * 16 + i) = *(v4f*)&lst[ni][i];
        }
    }
    __syncthreads();
    if (wx == 0 && quad == 0) {
#pragma unroll
        for (int ni = 0; ni < 2; ++ni) {
            const int rl = wy * 32 + ni * 16 + lane16;
            float nw[16];
#pragma unroll
            for (int i = 0; i < 16; ++i) nw[i] = mrg[rl * 16 + i];
            merge_top16(lst[ni], nw);
            float* dst = wsTop + ((size_t)(nbase + rl) * NSTRIPS + strip) * 16;
#pragma unroll
            for (int i = 0; i < 16; i += 4)
                *(float4*)(dst + i) = make_float4(lst[ni][i], lst[ni][i + 1],
                                                  lst[ni][i + 2], lst[ni][i + 3]);
        }
    }
}

// ------- stage2_fused: merge -> top-16 -> partials; last block finalizes ------
__global__ void stage2_fused(const float* __restrict__ wsTop,
                             const float* __restrict__ partialPos,
                             float* __restrict__ partialNeg,
                             unsigned int* __restrict__ ticket,
                             float* __restrict__ out) {
    __shared__ float red[128];
    __shared__ int isLast;
    int tid = blockIdx.x * 128 + threadIdx.x;   // 16384 threads, 128 blocks
    int row = tid >> 1, half = tid & 1;
    const float* src = wsTop + (size_t)row * (NSTRIPS * 16) + half * 64;
    float lst[16];
#pragma unroll
    for (int i = 0; i < 16; ++i) lst[i] = src[i];
#pragma unroll
    for (int c = 16; c < 64; c += 16) {
        float nw[16];
#pragma unroll
        for (int i = 0; i < 16; ++i) nw[i] = src[c + i];
        merge_top16(lst, nw);
    }
    {   // partner merge (adjacent lane, same wave)
        float nw[16];
        int pl = (threadIdx.x & 63) ^ 1;
#pragma unroll
        for (int i = 0; i < 16; ++i) nw[i] = __shfl(lst[i], pl, 64);
        merge_top16(lst, nw);
    }
    float s = 0.0f;
#pragma unroll
    for (int i = 0; i < 16; ++i) s += sat_exp(lst[i]);
    red[threadIdx.x] = half ? 0.0f : s;
    __syncthreads();
    for (int o = 64; o; o >>= 1) {
        if (threadIdx.x < o) red[threadIdx.x] += red[threadIdx.x + o];
        __syncthreads();
    }
    if (threadIdx.x == 0) partialNeg[blockIdx.x] = red[0];
    // ---- ticket: last block to finish performs the final reduction ----
    __threadfence();
    if (threadIdx.x == 0) isLast = (atomicAdd(ticket, 1u) == 127u) ? 1 : 0;
    __syncthreads();
    if (isLast) {
        float sp = 0.0f, sn = 0.0f;
        for (int i = threadIdx.x; i < 1024; i += 128) sp += partialPos[i];
        sn = partialNeg[threadIdx.x];
#pragma unroll
        for (int o = 32; o; o >>= 1) {
            sp += __shfl_xor(sp, o, 64);
            sn += __shfl_xor(sn, o, 64);
        }
        __syncthreads();   // red[] reuse
        if ((threadIdx.x & 63) == 0) {
            red[(threadIdx.x >> 6)] = sp;
            red[2 + (threadIdx.x >> 6)] = sn;
        }
        __syncthreads();
        if (threadIdx.x == 0) {
            float tp = red[0] + red[1];
            float tn = red[2] + red[3];
            out[0] = finite_or(-(tp / (float)BS), 0.0f);
            out[1] = finite_or(tn / (float)(BS * KNEG), 0.0f);
        }
    }
}

// ======================= legacy fallback (ws too small) ======================
__global__ void init_acc(float* acc) {
    if (threadIdx.x < 64) acc[threadIdx.x] = 0.0f;
}

__global__ void pos_kernel(const float* __restrict__ feat, float* __restrict__ acc) {
    int t = blockIdx.x * 256 + threadIdx.x;
    int row = t >> 4;
    int lane16 = t & 15;
    const float* f = feat + (size_t)row * 512 + lane16 * 16;
    float p = 0.0f;
#pragma unroll
    for (int q = 0; q < 16; q += 4) {
        float4 a = *(const float4*)(f + q);
        float4 b = *(const float4*)(f + 256 + q);
        p += a.x * b.x + a.y * b.y + a.z * b.z + a.w * b.w;
    }
#pragma unroll
    for (int o = 8; o; o >>= 1) p += __shfl_xor(p, o, 16);
    if (lane16 == 0) atomicAdd(&acc[0], sat_exp(p));
}

#define L_AOFF   0
#define L_BOFF   10240
#define L_PITCH  80
#define CPITCH  272
#define CWAVE   17408
#define L_SMEM  69632
__global__ __launch_bounds__(256, 2) void stage1_legacy(const float* __restrict__ feat,
                                                        float* __restrict__ wsTop) {
    __shared__ __align__(16) char smem[L_SMEM];
    const int t = threadIdx.x;
    const int l = t & 63;
    const int w = t >> 6;
    const int wy = w >> 1, wx = w & 1;
    const int quad = l >> 4, lane16 = l & 15;
    const int rowbase = blockIdx.x * 128;
    const int strip = blockIdx.y;
    char* cw = smem + w * CWAVE;
    const int grow = rowbase + wy * 64 + l;

    float lst[16];
#pragma unroll
    for (int i = 0; i < 16; ++i) lst[i] = -INFINITY;

    for (int ct = 0; ct < 4; ++ct) {
        const int colbase = strip * 1024 + ct * 256;
        v4f acc[4][8];
#pragma unroll
        for (int mi = 0; mi < 4; ++mi)
#pragma unroll
            for (int ni = 0; ni < 8; ++ni) acc[mi][ni] = (v4f)0.0f;
        for (int s = 0; s < 8; ++s) {
            const int k0 = s * 32;
            __syncthreads();
#pragma unroll
            for (int i = 0; i < 4; ++i) {
                int c = i * 256 + t;
                int r = c >> 3, chk = c & 7;
                float4 v = *(const float4*)(feat + (size_t)(rowbase + r) * 512 + k0 + chk * 4);
                uint2 pk;
                pk.x = (unsigned)f2bf_rne(v.x) | ((unsigned)f2bf_rne(v.y) << 16);
                pk.y = (unsigned)f2bf_rne(v.z) | ((unsigned)f2bf_rne(v.w) << 16);
                *(uint2*)(smem + L_AOFF + r * L_PITCH + chk * 8) = pk;
            }
#pragma unroll
            for (int i = 0; i < 8; ++i) {
                int c = i * 256 + t;
                int n = c >> 3, chk = c & 7;
                float4 v = *(const float4*)(feat + (size_t)(colbase + n) * 512 + 256 + k0 + chk * 4);
                uint2 pk;
                pk.x = (unsigned)f2bf_rne(v.x) | ((unsigned)f2bf_rne(v.y) << 16);
                pk.y = (unsigned)f2bf_rne(v.z) | ((unsigned)f2bf_rne(v.w) << 16);
                *(uint2*)(smem + L_BOFF + n * L_PITCH + chk * 8) = pk;
            }
            __syncthreads();
            s8b a[4];
#pragma unroll
            for (int mi = 0; mi < 4; ++mi)
                a[mi] = *(const s8b*)(smem + L_AOFF + (wy * 64 + mi * 16 + lane16) * L_PITCH + quad * 16);
#pragma unroll
            for (int ni = 0; ni < 8; ++ni) {
                s8b b = *(const s8b*)(smem + L_BOFF + (wx * 128 + ni * 16 + lane16) * L_PITCH + quad * 16);
#pragma unroll
                for (int mi = 0; mi < 4; ++mi)
                    acc[mi][ni] = __builtin_amdgcn_mfma_f32_16x16x32_bf16(a[mi], b, acc[mi][ni], 0, 0, 0);
            }
        }
#pragma unroll
        for (int h = 0; h < 2; ++h) {
            __syncthreads();
#pragma unroll
            for (int ni = 0; ni < 4; ++ni) {
                int c = ni * 16 + lane16;
#pragma unroll
                for (int mi = 0; mi < 4; ++mi)
                    *(v4f*)(cw + c * CPITCH + mi * 64 + quad * 16) = acc[mi][h * 4 + ni];
            }
            __syncthreads();
            const int gc0 = colbase + wx * 128 + h * 64;
            const int dj = grow - gc0;
#pragma unroll
            for (int j = 0; j < 64; ++j) {
                float v = *(const float*)(cw + j * CPITCH + l * 4);
                if (v > lst[0] && j != dj) topk_insert(lst, v);
            }
        }
    }
    float* dst = wsTop + (size_t)grow * 256 + strip * 32 + wx * 16;
#pragma unroll
    for (int i = 0; i < 16; i += 4)
        *(float4*)(dst + i) = make_float4(lst[i], lst[i + 1], lst[i + 2], lst[i + 3]);
}

__global__ void stage2_legacy(const float* __restrict__ wsTop, float* __restrict__ acc) {
    int row = blockIdx.x * blockDim.x + threadIdx.x;
    if (row >= BS) return;
    const float* src = wsTop + (size_t)row * 256;
    float lst[16];
#pragma unroll
    for (int i = 0; i < 16; ++i) lst[i] = -INFINITY;
    for (int c = 0; c < 256; c += 4) {
        float4 v4 = *(const float4*)(src + c);
        float vv[4] = {v4.x, v4.y, v4.z, v4.w};
#pragma unroll
        for (int j = 0; j < 4; ++j)
            if (vv[j] > lst[0]) topk_insert(lst, vv[j]);
    }
    float s = 0.0f;
#pragma unroll
    for (int i = 0; i < 16; ++i) s += sat_exp(lst[i]);
    atomicAdd(&acc[1], s);
}

__global__ void final_legacy(const float* __restrict__ acc, float* __restrict__ out) {
    if (threadIdx.x == 0) {
        out[0] = finite_or(-(acc[0] / (float)BS), 0.0f);
        out[1] = finite_or(acc[1] / (float)(BS * KNEG), 0.0f);
    }
}

extern "C" void kernel_launch(void* const* d_in, const int* in_sizes, int n_in,
                              void* d_out, int out_size, void* d_ws, size_t ws_size,
                              hipStream_t stream) {
    const float* feat = (const float*)d_in[0];
    float* out = (float*)d_out;

    // layout: featbf 8 MB | wsTop 4 MB | partialPos 4 KB | partialNeg 512 B | ticket
    unsigned short* featbf = (unsigned short*)d_ws;
    float* wsTop = (float*)(featbf + (size_t)BS * 512);
    float* partialPos = wsTop + (size_t)BS * NSTRIPS * 16;
    float* partialNeg = partialPos + 1024;
    unsigned int* ticket = (unsigned int*)(partialNeg + 128);
    const size_t need_new = (size_t)BS * 512 * 2 + (size_t)BS * NSTRIPS * 16 * 4
                          + (1024 + 128 + 1) * 4;

    if (ws_size >= need_new) {
        conv_pos<<<1024, 256, 0, stream>>>(feat, featbf, partialPos, ticket);
        stage1<<<dim3(128, NSTRIPS), 256, 0, stream>>>(featbf, wsTop);
        stage2_fused<<<128, 128, 0, stream>>>(wsTop, partialPos, partialNeg, ticket, out);
    } else {
        float* acc = (float*)d_ws;
        float* wsTopL = acc + 64;   // 8 MB legacy layout
        init_acc<<<1, 64, 0, stream>>>(acc);
        pos_kernel<<<512, 256, 0, stream>>>(feat, acc);
        stage1_legacy<<<dim3(64, 8), 256, 0, stream>>>(feat, wsTopL);
        stage2_legacy<<<32, 256, 0, stream>>>(wsTopL, acc);
        final_legacy<<<1, 1, 0, stream>>>(acc, out);
    }
}

// Round 15
// 133.949 us; speedup vs baseline: 1.0896x; 1.0896x over previous
//
#include <hip/hip_runtime.h>
#include <math.h>

#define BS   8192
#define DIM  256
#define KNEG 16
#define GAMMA (1.0f / 0.07f)
#define EXP_CLAMP 60.0f   // e^60*8192*16 ~ 1.5e31 < FLT_MAX: sums stay finite
#define NSTRIPS 8

typedef float v4f  __attribute__((ext_vector_type(4)));
typedef short s8b  __attribute__((ext_vector_type(8)));   // 8 bf16 as shorts

__device__ __forceinline__ float sat_exp(float dot) {
    float a = 2.0f * GAMMA * dot - 2.0f * GAMMA;
    return expf(fminf(a, EXP_CLAMP));
}

// compare-exchange: x=min, y=max (2 VALU, no selects)
__device__ __forceinline__ void ce(float& x, float& y) {
    float lo = fminf(x, y), hi = fmaxf(x, y);
    x = lo; y = hi;
}

// Batcher odd-even merge sort, 16 inputs, ascending. 63 CE.
__device__ __forceinline__ void sort16(float (&a)[16]) {
    ce(a[0],a[1]); ce(a[2],a[3]); ce(a[4],a[5]); ce(a[6],a[7]);
    ce(a[8],a[9]); ce(a[10],a[11]); ce(a[12],a[13]); ce(a[14],a[15]);
    ce(a[0],a[2]); ce(a[1],a[3]); ce(a[4],a[6]); ce(a[5],a[7]);
    ce(a[8],a[10]); ce(a[9],a[11]); ce(a[12],a[14]); ce(a[13],a[15]);
    ce(a[1],a[2]); ce(a[5],a[6]); ce(a[9],a[10]); ce(a[13],a[14]);
    ce(a[0],a[4]); ce(a[1],a[5]); ce(a[2],a[6]); ce(a[3],a[7]);
    ce(a[8],a[12]); ce(a[9],a[13]); ce(a[10],a[14]); ce(a[11],a[15]);
    ce(a[2],a[4]); ce(a[3],a[5]); ce(a[10],a[12]); ce(a[11],a[13]);
    ce(a[1],a[2]); ce(a[3],a[4]); ce(a[5],a[6]);
    ce(a[9],a[10]); ce(a[11],a[12]); ce(a[13],a[14]);
    ce(a[0],a[8]); ce(a[1],a[9]); ce(a[2],a[10]); ce(a[3],a[11]);
    ce(a[4],a[12]); ce(a[5],a[13]); ce(a[6],a[14]); ce(a[7],a[15]);
    ce(a[4],a[8]); ce(a[5],a[9]); ce(a[6],a[10]); ce(a[7],a[11]);
    ce(a[2],a[4]); ce(a[3],a[5]); ce(a[6],a[8]); ce(a[7],a[9]);
    ce(a[10],a[12]); ce(a[11],a[13]);
    ce(a[1],a[2]); ce(a[3],a[4]); ce(a[5],a[6]); ce(a[7],a[8]);
    ce(a[9],a[10]); ce(a[11],a[12]); ce(a[13],a[14]);
}

// merge two ascending sorted-16, keep top-16 ascending (16 max + 32 CE)
__device__ __forceinline__ void merge_top16(float (&lst)[16], const float (&nw)[16]) {
#pragma unroll
    for (int i = 0; i < 16; ++i) lst[i] = fmaxf(lst[i], nw[15 - i]);
#pragma unroll
    for (int j = 8; j > 0; j >>= 1)
#pragma unroll
        for (int i = 0; i < 16; ++i) {
            int ixj = i ^ j;
            if (ixj > i) ce(lst[i], lst[ixj]);
        }
}

// legacy insertion helper (fallback path only)
__device__ __forceinline__ void topk_insert(float (&lst)[16], float v) {
    float nl[16];
#pragma unroll
    for (int u = 0; u < 15; ++u)
        nl[u] = (v > lst[u + 1]) ? lst[u + 1] : ((v > lst[u]) ? v : lst[u]);
    nl[15] = (v > lst[15]) ? v : lst[15];
#pragma unroll
    for (int u = 0; u < 16; ++u) lst[u] = nl[u];
}

__device__ __forceinline__ unsigned short f2bf_rne(float f) {
    unsigned int u = __float_as_uint(f);
    u += 0x7FFFu + ((u >> 16) & 1u);
    return (unsigned short)(u >> 16);
}

__device__ __forceinline__ void gld_lds16(const void* g, void* l) {
    __builtin_amdgcn_global_load_lds(
        (const __attribute__((address_space(1))) void*)g,
        (__attribute__((address_space(3))) void*)l, 16, 0, 0);
}

__device__ __forceinline__ float finite_or(float x, float repl) {
    if (isnan(x)) return repl;
    if (isinf(x)) return x > 0.0f ? 3.0e38f : -3.0e38f;
    return x;
}

// ------- conv_pos: fp32 -> bf16 pre-convert + per-block diagonal partials -----
__global__ void conv_pos(const float* __restrict__ feat,
                         unsigned short* __restrict__ featbf,
                         float* __restrict__ partialPos) {
    __shared__ float red[8];
    int t = blockIdx.x * 256 + threadIdx.x;   // 0..262143
    int row = t >> 5;
    int c = t & 31;                           // 8-float chunk within the 256-dim
    const float* f1 = feat + (size_t)row * 512 + c * 8;
    const float* f2 = f1 + 256;
    float4 a0 = *(const float4*)(f1);
    float4 a1 = *(const float4*)(f1 + 4);
    float4 b0 = *(const float4*)(f2);
    float4 b1 = *(const float4*)(f2 + 4);
    uint4 pa, pb;
    pa.x = (unsigned)f2bf_rne(a0.x) | ((unsigned)f2bf_rne(a0.y) << 16);
    pa.y = (unsigned)f2bf_rne(a0.z) | ((unsigned)f2bf_rne(a0.w) << 16);
    pa.z = (unsigned)f2bf_rne(a1.x) | ((unsigned)f2bf_rne(a1.y) << 16);
    pa.w = (unsigned)f2bf_rne(a1.z) | ((unsigned)f2bf_rne(a1.w) << 16);
    pb.x = (unsigned)f2bf_rne(b0.x) | ((unsigned)f2bf_rne(b0.y) << 16);
    pb.y = (unsigned)f2bf_rne(b0.z) | ((unsigned)f2bf_rne(b0.w) << 16);
    pb.z = (unsigned)f2bf_rne(b1.x) | ((unsigned)f2bf_rne(b1.y) << 16);
    pb.w = (unsigned)f2bf_rne(b1.z) | ((unsigned)f2bf_rne(b1.w) << 16);
    *(uint4*)(featbf + (size_t)row * 512 + c * 8) = pa;
    *(uint4*)(featbf + (size_t)row * 512 + 256 + c * 8) = pb;
    float p = a0.x * b0.x + a0.y * b0.y + a0.z * b0.z + a0.w * b0.w
            + a1.x * b1.x + a1.y * b1.y + a1.z * b1.z + a1.w * b1.w;
#pragma unroll
    for (int o = 16; o; o >>= 1) p += __shfl_xor(p, o, 32);
    if (c == 0) red[threadIdx.x >> 5] = sat_exp(p);
    __syncthreads();
    if (threadIdx.x == 0) {
        float s = 0.0f;
#pragma unroll
        for (int i = 0; i < 8; ++i) s += red[i];
        partialPos[blockIdx.x] = s;
    }
}

// ---------------- stage1: R11 structure (best) + wave-uniform diagonal hoist --
// Block 256 thr = 4 waves (wy=row-half, wx=col-half). 16x16x32 MFMA.
// B (64 F1 rows x K=256) LDS-resident 32 KB (xor-swizzled).
// A (128 F2 cols x BK=32) double-buffered 2x8 KB, single barrier per k-step,
// prefetch issued right after the barrier. Diagonal masking runs only in the
// one (strip, ct) that can contain col==row (wave-uniform skip otherwise).
#define A_OFF  32768
#define S1_LDS 49152

__global__ __launch_bounds__(256, 3) void stage1(const unsigned short* __restrict__ featbf,
                                                 float* __restrict__ wsTop) {
    __shared__ __align__(16) char smem[S1_LDS];
    const int t = threadIdx.x;
    const int l = t & 63;
    const int w = t >> 6;
    const int wy = w >> 1, wx = w & 1;
    const int quad = l >> 4, lane16 = l & 15;
    const int nbase = blockIdx.x * 64;
    const int strip = blockIdx.y;
    // diagonal lives only in this strip/ct (64 rows never straddle a 128-col ct)
    const bool dstrip = (strip == (nbase >> 10));
    const int dct = (nbase & 1023) >> 7;

    // ---- stage B resident: rows nbase..nbase+63 (F1), all K, swizzled ----
#pragma unroll
    for (int jj = 0; jj < 8; ++jj) {
        int j = w * 8 + jj;
        int r = 2 * j + (l >> 5);
        int c = (l & 31) ^ (r & 31);
        gld_lds16(featbf + ((size_t)(nbase + r) << 9) + c * 8, smem + j * 1024);
    }

    float lst[2][16];
#pragma unroll
    for (int ni = 0; ni < 2; ++ni)
#pragma unroll
        for (int i = 0; i < 16; ++i) lst[ni][i] = -INFINITY;

    const int akey = (quad ^ ((lane16 >> 1) & 3)) * 16;   // A frag slot offset
    const int sj_r = l >> 2;                              // A staging row-in-group
    const int sj_s = l & 3;                               // A staging slot

    // initial prefetch: ct=0, s=0 -> buf0 (B staging still in flight; fine)
    {
        const int ctbase = strip * 1024;
#pragma unroll
        for (int jj = 0; jj < 2; ++jj) {
            int j = w * 2 + jj;
            int r = 16 * j + sj_r;
            int c = sj_s ^ ((r >> 1) & 3);
            gld_lds16(featbf + ((size_t)(ctbase + r) << 9) + 256 + c * 8,
                      smem + A_OFF + j * 1024);
        }
    }

#pragma unroll 1
    for (int ct = 0; ct < 8; ++ct) {
        const int ctbase = strip * 1024 + ct * 128;
        v4f acc[4][2];
#pragma unroll
        for (int mi = 0; mi < 4; ++mi)
#pragma unroll
            for (int ni = 0; ni < 2; ++ni) acc[mi][ni] = (v4f)0.0f;

#pragma unroll
        for (int s = 0; s < 8; ++s) {
            __syncthreads();   // drains prefetch for THIS step (issued a phase ago)
            // prefetch next k-chunk into the other buffer
            if (ct < 7 || s < 7) {
                const int nct = (s == 7) ? ctbase + 128 : ctbase;
                const int ns = (s == 7) ? 0 : s + 1;
                char* dst = smem + A_OFF + ((s + 1) & 1) * 8192;
#pragma unroll
                for (int jj = 0; jj < 2; ++jj) {
                    int j = w * 2 + jj;
                    int r = 16 * j + sj_r;
                    int c = sj_s ^ ((r >> 1) & 3);
                    gld_lds16(featbf + ((size_t)(nct + r) << 9) + 256 + ns * 32 + c * 8,
                              dst + j * 1024);
                }
            }
            // compute current chunk
            const char* Ab = smem + A_OFF + (s & 1) * 8192;
            s8b a[4];
#pragma unroll
            for (int mi = 0; mi < 4; ++mi)
                a[mi] = *(const s8b*)(Ab + (wx * 64 + mi * 16 + lane16) * 64 + akey);
#pragma unroll
            for (int ni = 0; ni < 2; ++ni) {
                int n31 = ni * 16 + lane16;
                s8b b = *(const s8b*)(smem
                    + (wy * 32 + n31) * 512 + (((s * 4 + quad) ^ n31) & 31) * 16);
#pragma unroll
                for (int mi = 0; mi < 4; ++mi)
                    acc[mi][ni] = __builtin_amdgcn_mfma_f32_16x16x32_bf16(
                        a[mi], b, acc[mi][ni], 0, 0, 0);
            }
        }
        // ---- batch scan: 16 fresh values per ni -> Batcher sort + merge ----
        const bool dohere = dstrip && (ct == dct);   // wave-uniform
#pragma unroll
        for (int ni = 0; ni < 2; ++ni) {
            float nw[16];
#pragma unroll
            for (int mi = 0; mi < 4; ++mi)
#pragma unroll
                for (int r4 = 0; r4 < 4; ++r4)
                    nw[mi * 4 + r4] = acc[mi][ni][r4];
            if (dohere) {   // diagonal mask: only 1 of 64 (strip,ct) batches
                const int row = nbase + wy * 32 + ni * 16 + lane16;
#pragma unroll
                for (int mi = 0; mi < 4; ++mi) {
                    const int c0 = ctbase + wx * 64 + mi * 16 + quad * 4;
#pragma unroll
                    for (int r4 = 0; r4 < 4; ++r4)
                        if (c0 + r4 == row) nw[mi * 4 + r4] = -INFINITY;
                }
            }
            sort16(nw);
            merge_top16(lst[ni], nw);
        }
    }
    // ---- quad merge via xor-shfl (lists sorted ascending) ----
#pragma unroll
    for (int ni = 0; ni < 2; ++ni) {
#pragma unroll
        for (int r = 16; r <= 32; r <<= 1) {
            float nw[16];
#pragma unroll
            for (int i = 0; i < 16; ++i) nw[i] = __shfl(lst[ni][i], l ^ r, 64);
            merge_top16(lst[ni], nw);
        }
    }
    // ---- wx merge via LDS (A buffers idle: last prefetch consumed) ----
    __syncthreads();
    float* mrg = (float*)(smem + A_OFF);   // 64 rows x 16 f32 = 4 KB
    if (wx == 1 && quad == 0) {
#pragma unroll
        for (int ni = 0; ni < 2; ++ni) {
            int rl = wy * 32 + ni * 16 + lane16;
#pragma unroll
            for (int i = 0; i < 16; i += 4)
                *(v4f*)(mrg + rl * 16 + i) = *(v4f*)&lst[ni][i];
        }
    }
    __syncthreads();
    if (wx == 0 && quad == 0) {
#pragma unroll
        for (int ni = 0; ni < 2; ++ni) {
            const int rl = wy * 32 + ni * 16 + lane16;
            float nw[16];
#pragma unroll
            for (int i = 0; i < 16; ++i) nw[i] = mrg[rl * 16 + i];
            merge_top16(lst[ni], nw);
            float* dst = wsTop + ((size_t)(nbase + rl) * NSTRIPS + strip) * 16;
#pragma unroll
            for (int i = 0; i < 16; i += 4)
                *(float4*)(dst + i) = make_float4(lst[ni][i], lst[ni][i + 1],
                                                  lst[ni][i + 2], lst[ni][i + 3]);
        }
    }
}

// ------- stage2: 2 threads/row, merge 8 sorted lists -> top-16 -> partials ----
__global__ void stage2_fast(const float* __restrict__ wsTop, float* __restrict__ partialNeg) {
    __shared__ float red[128];
    int tid = blockIdx.x * 128 + threadIdx.x;   // 16384 threads, 128 blocks
    int row = tid >> 1, half = tid & 1;
    const float* src = wsTop + (size_t)row * (NSTRIPS * 16) + half * 64;
    float lst[16];
#pragma unroll
    for (int i = 0; i < 16; ++i) lst[i] = src[i];
#pragma unroll
    for (int c = 16; c < 64; c += 16) {
        float nw[16];
#pragma unroll
        for (int i = 0; i < 16; ++i) nw[i] = src[c + i];
        merge_top16(lst, nw);
    }
    {   // partner merge (adjacent lane, same wave)
        float nw[16];
        int pl = (threadIdx.x & 63) ^ 1;
#pragma unroll
        for (int i = 0; i < 16; ++i) nw[i] = __shfl(lst[i], pl, 64);
        merge_top16(lst, nw);
    }
    float s = 0.0f;
#pragma unroll
    for (int i = 0; i < 16; ++i) s += sat_exp(lst[i]);
    red[threadIdx.x] = half ? 0.0f : s;
    __syncthreads();
    for (int o = 64; o; o >>= 1) {
        if (threadIdx.x < o) red[threadIdx.x] += red[threadIdx.x + o];
        __syncthreads();
    }
    if (threadIdx.x == 0) partialNeg[blockIdx.x] = red[0];
}

// ---------------- final: reduce partials, sanitize inf/nan ----------------
__global__ void final_kernel(const float* __restrict__ partialPos,
                             const float* __restrict__ partialNeg,
                             float* __restrict__ out) {
    __shared__ float w1[4], w2[4];
    float sp = 0.0f, sn = 0.0f;
    for (int i = threadIdx.x; i < 1024; i += 256) sp += partialPos[i];
    if (threadIdx.x < 128) sn = partialNeg[threadIdx.x];
#pragma unroll
    for (int o = 32; o; o >>= 1) {
        sp += __shfl_xor(sp, o, 64);
        sn += __shfl_xor(sn, o, 64);
    }
    if ((threadIdx.x & 63) == 0) {
        w1[threadIdx.x >> 6] = sp;
        w2[threadIdx.x >> 6] = sn;
    }
    __syncthreads();
    if (threadIdx.x == 0) {
        float tp = w1[0] + w1[1] + w1[2] + w1[3];
        float tn = w2[0] + w2[1] + w2[2] + w2[3];
        out[0] = finite_or(-(tp / (float)BS), 0.0f);
        out[1] = finite_or(tn / (float)(BS * KNEG), 0.0f);
    }
}

// ======================= legacy fallback (ws too small) ======================
__global__ void init_acc(float* acc) {
    if (threadIdx.x < 64) acc[threadIdx.x] = 0.0f;
}

__global__ void pos_kernel(const float* __restrict__ feat, float* __restrict__ acc) {
    int t = blockIdx.x * 256 + threadIdx.x;
    int row = t >> 4;
    int lane16 = t & 15;
    const float* f = feat + (size_t)row * 512 + lane16 * 16;
    float p = 0.0f;
#pragma unroll
    for (int q = 0; q < 16; q += 4) {
        float4 a = *(const float4*)(f + q);
        float4 b = *(const float4*)(f + 256 + q);
        p += a.x * b.x + a.y * b.y + a.z * b.z + a.w * b.w;
    }
#pragma unroll
    for (int o = 8; o; o >>= 1) p += __shfl_xor(p, o, 16);
    if (lane16 == 0) atomicAdd(&acc[0], sat_exp(p));
}

#define L_AOFF   0
#define L_BOFF   10240
#define L_PITCH  80
#define CPITCH  272
#define CWAVE   17408
#define L_SMEM  69632
__global__ __launch_bounds__(256, 2) void stage1_legacy(const float* __restrict__ feat,
                                                        float* __restrict__ wsTop) {
    __shared__ __align__(16) char smem[L_SMEM];
    const int t = threadIdx.x;
    const int l = t & 63;
    const int w = t >> 6;
    const int wy = w >> 1, wx = w & 1;
    const int quad = l >> 4, lane16 = l & 15;
    const int rowbase = blockIdx.x * 128;
    const int strip = blockIdx.y;
    char* cw = smem + w * CWAVE;
    const int grow = rowbase + wy * 64 + l;

    float lst[16];
#pragma unroll
    for (int i = 0; i < 16; ++i) lst[i] = -INFINITY;

    for (int ct = 0; ct < 4; ++ct) {
        const int colbase = strip * 1024 + ct * 256;
        v4f acc[4][8];
#pragma unroll
        for (int mi = 0; mi < 4; ++mi)
#pragma unroll
            for (int ni = 0; ni < 8; ++ni) acc[mi][ni] = (v4f)0.0f;
        for (int s = 0; s < 8; ++s) {
            const int k0 = s * 32;
            __syncthreads();
#pragma unroll
            for (int i = 0; i < 4; ++i) {
                int c = i * 256 + t;
                int r = c >> 3, chk = c & 7;
                float4 v = *(const float4*)(feat + (size_t)(rowbase + r) * 512 + k0 + chk * 4);
                uint2 pk;
                pk.x = (unsigned)f2bf_rne(v.x) | ((unsigned)f2bf_rne(v.y) << 16);
                pk.y = (unsigned)f2bf_rne(v.z) | ((unsigned)f2bf_rne(v.w) << 16);
                *(uint2*)(smem + L_AOFF + r * L_PITCH + chk * 8) = pk;
            }
#pragma unroll
            for (int i = 0; i < 8; ++i) {
                int c = i * 256 + t;
                int n = c >> 3, chk = c & 7;
                float4 v = *(const float4*)(feat + (size_t)(colbase + n) * 512 + 256 + k0 + chk * 4);
                uint2 pk;
                pk.x = (unsigned)f2bf_rne(v.x) | ((unsigned)f2bf_rne(v.y) << 16);
                pk.y = (unsigned)f2bf_rne(v.z) | ((unsigned)f2bf_rne(v.w) << 16);
                *(uint2*)(smem + L_BOFF + n * L_PITCH + chk * 8) = pk;
            }
            __syncthreads();
            s8b a[4];
#pragma unroll
            for (int mi = 0; mi < 4; ++mi)
                a[mi] = *(const s8b*)(smem + L_AOFF + (wy * 64 + mi * 16 + lane16) * L_PITCH + quad * 16);
#pragma unroll
            for (int ni = 0; ni < 8; ++ni) {
                s8b b = *(const s8b*)(smem + L_BOFF + (wx * 128 + ni * 16 + lane16) * L_PITCH + quad * 16);
#pragma unroll
                for (int mi = 0; mi < 4; ++mi)
                    acc[mi][ni] = __builtin_amdgcn_mfma_f32_16x16x32_bf16(a[mi], b, acc[mi][ni], 0, 0, 0);
            }
        }
#pragma unroll
        for (int h = 0; h < 2; ++h) {
            __syncthreads();
#pragma unroll
            for (int ni = 0; ni < 4; ++ni) {
                int c = ni * 16 + lane16;
#pragma unroll
                for (int mi = 0; mi < 4; ++mi)
                    *(v4f*)(cw + c * CPITCH + mi * 64 + quad * 16) = acc[mi][h * 4 + ni];
            }
            __syncthreads();
            const int gc0 = colbase + wx * 128 + h * 64;
            const int dj = grow - gc0;
#pragma unroll
            for (int j = 0; j < 64; ++j) {
                float v = *(const float*)(cw + j * CPITCH + l * 4);
                if (v > lst[0] && j != dj) topk_insert(lst, v);
            }
        }
    }
    float* dst = wsTop + (size_t)grow * 256 + strip * 32 + wx * 16;
#pragma unroll
    for (int i = 0; i < 16; i += 4)
        *(float4*)(dst + i) = make_float4(lst[i], lst[i + 1], lst[i + 2], lst[i + 3]);
}

__global__ void stage2_legacy(const float* __restrict__ wsTop, float* __restrict__ acc) {
    int row = blockIdx.x * blockDim.x + threadIdx.x;
    if (row >= BS) return;
    const float* src = wsTop + (size_t)row * 256;
    float lst[16];
#pragma unroll
    for (int i = 0; i < 16; ++i) lst[i] = -INFINITY;
    for (int c = 0; c < 256; c += 4) {
        float4 v4 = *(const float4*)(src + c);
        float vv[4] = {v4.x, v4.y, v4.z, v4.w};
#pragma unroll
        for (int j = 0; j < 4; ++j)
            if (vv[j] > lst[0]) topk_insert(lst, vv[j]);
    }
    float s = 0.0f;
#pragma unroll
    for (int i = 0; i < 16; ++i) s += sat_exp(lst[i]);
    atomicAdd(&acc[1], s);
}

__global__ void final_legacy(const float* __restrict__ acc, float* __restrict__ out) {
    if (threadIdx.x == 0) {
        out[0] = finite_or(-(acc[0] / (float)BS), 0.0f);
        out[1] = finite_or(acc[1] / (float)(BS * KNEG), 0.0f);
    }
}

extern "C" void kernel_launch(void* const* d_in, const int* in_sizes, int n_in,
                              void* d_out, int out_size, void* d_ws, size_t ws_size,
                              hipStream_t stream) {
    const float* feat = (const float*)d_in[0];
    float* out = (float*)d_out;

    // layout: featbf 8 MB | wsTop 4 MB | partialPos 4 KB | partialNeg 512 B
    unsigned short* featbf = (unsigned short*)d_ws;
    float* wsTop = (float*)(featbf + (size_t)BS * 512);
    float* partialPos = wsTop + (size_t)BS * NSTRIPS * 16;
    float* partialNeg = partialPos + 1024;
    const size_t need_new = (size_t)BS * 512 * 2 + (size_t)BS * NSTRIPS * 16 * 4
                          + (1024 + 128) * 4;

    if (ws_size >= need_new) {
        conv_pos<<<1024, 256, 0, stream>>>(feat, featbf, partialPos);
        stage1<<<dim3(128, NSTRIPS), 256, 0, stream>>>(featbf, wsTop);
        stage2_fast<<<128, 128, 0, stream>>>(wsTop, partialNeg);
        final_kernel<<<1, 256, 0, stream>>>(partialPos, partialNeg, out);
    } else {
        float* acc = (float*)d_ws;
        float* wsTopL = acc + 64;   // 8 MB legacy layout
        init_acc<<<1, 64, 0, stream>>>(acc);
        pos_kernel<<<512, 256, 0, stream>>>(feat, acc);
        stage1_legacy<<<dim3(64, 8), 256, 0, stream>>>(feat, wsTopL);
        stage2_legacy<<<32, 256, 0, stream>>>(wsTopL, acc);
        final_legacy<<<1, 1, 0, stream>>>(acc, out);
    }
}